// Round 6
// baseline (4458.077 us; speedup 1.0000x reference)
//
#include <hip/hip_runtime.h>
#include <math.h>

typedef short short8 __attribute__((ext_vector_type(8)));
typedef float f32x4 __attribute__((ext_vector_type(4)));
typedef unsigned short u16;
typedef u16 us4 __attribute__((ext_vector_type(4)));

#define DEVI static __device__ __forceinline__

constexpr float SCALE_Q = 0.17677669529663687f;  // 32^-0.5

DEVI u16 f2bf(float f) {
  unsigned u = __builtin_bit_cast(unsigned, f);
  u += 0x7FFFu + ((u >> 16) & 1u);
  return (u16)(u >> 16);
}

// async global->LDS, 16B per lane; lds dest = wave-uniform base + lane*16
DEVI void gload16(const u16* g, u16* l) {
  __builtin_amdgcn_global_load_lds((const __attribute__((address_space(1))) void*)g,
                                   (__attribute__((address_space(3))) void*)l,
                                   16, 0, 0);
}

// ---------------- weight fp32 -> bf16 ----------------
__global__ void cvt_bf16(const float4* __restrict__ src, us4* __restrict__ dst, int n4) {
  int i = blockIdx.x * 256 + threadIdx.x;
  if (i < n4) {
    float4 v = src[i];
    us4 o = { f2bf(v.x), f2bf(v.y), f2bf(v.z), f2bf(v.w) };
    dst[i] = o;
  }
}

// qkv weights: permute rows so out col' = which*512 + head*32 + d  (src col = head*96 + d*3 + which)
__global__ void cvt_qkvw(const float4* __restrict__ src, us4* __restrict__ dst) {
  int i = blockIdx.x * 256 + threadIdx.x;   // 1536 rows x 128 float4
  int row = i >> 7, c4 = i & 127;
  int which = row >> 9, head = (row >> 5) & 15, d = row & 31;
  int srow = head * 96 + d * 3 + which;
  float4 v = src[srow * 128 + c4];
  us4 o = { f2bf(v.x), f2bf(v.y), f2bf(v.z), f2bf(v.w) };
  dst[i] = o;
}

__global__ void perm_qkvb(const float* __restrict__ src, float* __restrict__ dst) {
  int i = blockIdx.x * 256 + threadIdx.x;   // 1536
  int which = i >> 9, head = (i >> 5) & 15, d = i & 31;
  dst[i] = src[head * 96 + d * 3 + which];
}

// ---------------- LayerNorm (+ optional roll + dilated window partition) ----------------
template<bool PERM>
__global__ __launch_bounds__(256) void ln_kernel(const float* __restrict__ src,
                                                 const float* __restrict__ gw,
                                                 const float* __restrict__ gb,
                                                 u16* __restrict__ dst) {
  int wid = threadIdx.x >> 6, lane = threadIdx.x & 63;
  int m = blockIdx.x * 4 + wid;
  int srow;
  if (PERM) {
    int b = m >> 12;
    int win = (m >> 6) & 63, t = m & 63;
    int i2 = win >> 3, j2 = win & 7, s1 = t >> 3, s2 = t & 7;
    int h = (s1 * 8 + i2 + 4) & 63, w = (s2 * 8 + j2 + 4) & 63;
    srow = (b << 12) + h * 64 + w;
  } else {
    srow = m;
  }
  const float4* r4 = (const float4*)(src + (size_t)srow * 512);
  float4 v0 = r4[lane], v1 = r4[lane + 64];
  float s  = v0.x + v0.y + v0.z + v0.w + v1.x + v1.y + v1.z + v1.w;
  float ss = v0.x*v0.x + v0.y*v0.y + v0.z*v0.z + v0.w*v0.w
           + v1.x*v1.x + v1.y*v1.y + v1.z*v1.z + v1.w*v1.w;
  #pragma unroll
  for (int off = 1; off < 64; off <<= 1) {
    s  += __shfl_xor(s, off);
    ss += __shfl_xor(ss, off);
  }
  float mean = s * (1.f/512.f);
  float var  = ss * (1.f/512.f) - mean*mean;
  float rstd = rsqrtf(var + 1e-5f);
  const float4* w4 = (const float4*)gw;
  const float4* b4 = (const float4*)gb;
  float4 wa = w4[lane], ba = b4[lane], wb = w4[lane+64], bb = b4[lane+64];
  us4 o0 = { f2bf((v0.x-mean)*rstd*wa.x + ba.x),
             f2bf((v0.y-mean)*rstd*wa.y + ba.y),
             f2bf((v0.z-mean)*rstd*wa.z + ba.z),
             f2bf((v0.w-mean)*rstd*wa.w + ba.w) };
  us4 o1 = { f2bf((v1.x-mean)*rstd*wb.x + bb.x),
             f2bf((v1.y-mean)*rstd*wb.y + bb.y),
             f2bf((v1.z-mean)*rstd*wb.z + bb.z),
             f2bf((v1.w-mean)*rstd*wb.w + bb.w) };
  us4* d4 = (us4*)(dst + (size_t)m * 512);
  d4[lane] = o0; d4[lane + 64] = o1;
}

// ---------------- GEMM: C[M,N] = A[M,K](bf16) @ W[N,K]^T(bf16) + bias ----
// 256x256 tile, BK=32, 8 waves (2Mx4N), ring-2 LDS (2 x 32 KiB = 64 KiB) -> 2 blocks/CU.
// Per K-tile: {stage kt+1 (4 gload16) | ds_read + 2x16 MFMA on buf kt | vmcnt(0) | barrier}.
// Cover = full tile of compute; occupancy (4 waves/SIMD) fills remaining bubbles.
// MODE 0: qkv (permuted cols: tn 0-1 q(scaled), 2-3 k, 4-5 v(transposed))
// MODE 1: proj: fo[win_reverse(row), col] = resid[same] + val (fp32 direct)
// MODE 2: fc1: gelu(tanh-approx) -> o0 bf16 row-major
// MODE 3: fc2: fo[row*512+col] += val (fp32 direct)
template<int MODE>
__global__ __launch_bounds__(512, 4) void gemm_k(const u16* __restrict__ A,
                                                 const u16* __restrict__ Bw,
                                                 const float* __restrict__ bias,
                                                 u16* __restrict__ o0, u16* __restrict__ o1,
                                                 u16* __restrict__ o2,
                                                 float* __restrict__ fo,
                                                 const float* __restrict__ resid,
                                                 int M, int N, int K) {
  __shared__ u16 LDS[2][2][8192];   // [buf][A/B][256 rows x 32 k] = 64 KiB
  int nt = N >> 8;
  int nwg = gridDim.x, cpx = nwg >> 3, bid = blockIdx.x;
  int swz = (bid & 7) * cpx + (bid >> 3);
  int tm = swz / nt, tn = swz % nt;
  int tid = threadIdx.x, lane = tid & 63, wv = tid >> 6;
  int wm = wv >> 2, wn = wv & 3;       // 2 M-halves x 4 N-quarters
  int rr = lane & 15, g = lane >> 4;
  int NT = K >> 5;

  // staging: thread covers rows (tid>>2) and (tid>>2)+128 at k-chunk tid&3;
  // source k-chunk pre-XORed: ga = (ch - (r>>1)) & 3  (read side applies inverse)
  int rA = tid >> 2, ch = tid & 3;
  int ga = (ch - (rA >> 1)) & 3;
  const u16* a0 = A  + (size_t)(tm * 256 + rA) * K + ga * 8;
  const u16* b0 = Bw + (size_t)(tn * 256 + rA) * K + ga * 8;
  size_t rskip = (size_t)128 * K;

#define STG(kt, buf) { \
    u16* dA = &LDS[buf][0][0] + (wv << 9); u16* dB = &LDS[buf][1][0] + (wv << 9); \
    gload16(a0 + (kt) * 32, dA); gload16(a0 + rskip + (kt) * 32, dA + 4096); \
    gload16(b0 + (kt) * 32, dB); gload16(b0 + rskip + (kt) * 32, dB + 4096); }

  f32x4 acc[8][4] = {};

  STG(0, 0);
  asm volatile("s_waitcnt vmcnt(0)" ::: "memory");
  __builtin_amdgcn_s_barrier();

  for (int kt = 0; kt < NT; ++kt) {
    int c = kt & 1;
    if (kt + 1 < NT) STG(kt + 1, c ^ 1);
    const u16* AT = &LDS[c][0][0];
    const u16* BT = &LDS[c][1][0];
    short8 bf[4], af[4], af2[4];
    #pragma unroll
    for (int ni = 0; ni < 4; ni++) {
      int r = wn * 64 + ni * 16 + rr;
      bf[ni] = *(const short8*)(BT + r * 32 + (((g + (r >> 1)) & 3) << 3));
    }
    #pragma unroll
    for (int mi = 0; mi < 4; mi++) {
      int r = wm * 128 + mi * 16 + rr;
      af[mi] = *(const short8*)(AT + r * 32 + (((g + (r >> 1)) & 3) << 3));
    }
    __builtin_amdgcn_s_setprio(1);
    #pragma unroll
    for (int mi = 0; mi < 4; mi++)
      #pragma unroll
      for (int ni = 0; ni < 4; ni++)
        acc[mi][ni] = __builtin_amdgcn_mfma_f32_16x16x32_bf16(af[mi], bf[ni], acc[mi][ni], 0, 0, 0);
    __builtin_amdgcn_s_setprio(0);
    #pragma unroll
    for (int mi = 0; mi < 4; mi++) {
      int r = wm * 128 + 64 + mi * 16 + rr;
      af2[mi] = *(const short8*)(AT + r * 32 + (((g + (r >> 1)) & 3) << 3));
    }
    __builtin_amdgcn_s_setprio(1);
    #pragma unroll
    for (int mi = 0; mi < 4; mi++)
      #pragma unroll
      for (int ni = 0; ni < 4; ni++)
        acc[4 + mi][ni] = __builtin_amdgcn_mfma_f32_16x16x32_bf16(af2[mi], bf[ni], acc[4 + mi][ni], 0, 0, 0);
    __builtin_amdgcn_s_setprio(0);
    asm volatile("s_waitcnt vmcnt(0)" ::: "memory");   // kt+1 landed; cover = this tile's compute
    __builtin_amdgcn_s_barrier();
  }
#undef STG

  // epilogue: per-wave 8 KiB LDS bounce (wave-private -> no barriers), two 64-row halves
  u16* wreg = &LDS[0][0][0] + wv * 4096;
  int rb0 = tm * 256 + wm * 128;
  int cb0 = tn * 256 + wn * 64;

  if (MODE == 0 || MODE == 2) {
    bool isV = (MODE == 0) && (tn >= 4);
    #pragma unroll
    for (int half = 0; half < 2; half++) {
      if (!isV) {
        #pragma unroll
        for (int mi2 = 0; mi2 < 4; mi2++)
          #pragma unroll
          for (int ni = 0; ni < 4; ni++) {
            float bv = bias[cb0 + ni * 16 + rr];
            #pragma unroll
            for (int r = 0; r < 4; r++) {
              float val = acc[half * 4 + mi2][ni][r] + bv;
              if (MODE == 2) {
                float u = val * (0.79788456f + 0.03567740814f * val * val);
                float e = __expf(2.f * u);
                val = val * (1.f - __builtin_amdgcn_rcpf(e + 1.f));
              }
              if (MODE == 0 && tn < 2) val *= SCALE_Q;
              int row = mi2 * 16 + g * 4 + r;
              int col = ni * 16 + rr;
              wreg[row * 64 + (((col >> 3) ^ (row & 7)) << 3) + (col & 7)] = f2bf(val);
            }
          }
        int row = lane;
        #pragma unroll
        for (int chk = 0; chk < 8; chk++) {
          short8 vd = *(const short8*)&wreg[row * 64 + ((chk ^ (row & 7)) << 3)];
          if (MODE == 2) {
            size_t grow = (size_t)rb0 + half * 64 + row;
            *(short8*)(o0 + grow * N + cb0 + chk * 8) = vd;
          } else {
            int grow = rb0 + half * 64 + row;
            int w = grow >> 6, tt = grow & 63;
            int head = ((cb0 & 511) >> 5) + (chk >> 2);
            u16* dst = (tn < 2) ? o0 : o1;
            *(short8*)(dst + ((size_t)(w * 16 + head) * 64 + tt) * 32 + (chk & 3) * 8) = vd;
          }
        }
      } else {
        // v: transposed deposit; half covers t-rows [half*64, half*64+64)
        #pragma unroll
        for (int mi2 = 0; mi2 < 4; mi2++)
          #pragma unroll
          for (int ni = 0; ni < 4; ni++) {
            float bv = bias[cb0 + ni * 16 + rr];
            #pragma unroll
            for (int r = 0; r < 4; r++) {
              float val = acc[half * 4 + mi2][ni][r] + bv;
              int row = mi2 * 16 + g * 4 + r;   // t within half (0..63)
              int col = ni * 16 + rr;           // d within wave cols (0..63)
              wreg[col * 64 + (((row >> 3) ^ (col & 7)) << 3) + (row & 7)] = f2bf(val);
            }
          }
        int cb0v = cb0 - 1024;
        int col = lane;
        int head = (cb0v + col) >> 5, d = (cb0v + col) & 31;
        int grow = rb0 + half * 64;
        int w = grow >> 6;
        #pragma unroll
        for (int chk = 0; chk < 8; chk++) {
          short8 vd = *(const short8*)&wreg[col * 64 + ((chk ^ (col & 7)) << 3)];
          *(short8*)(o2 + ((size_t)(w * 16 + head) * 32 + d) * 64 + (grow & 63) + chk * 8) = vd;
        }
      }
    }
  } else {
    #pragma unroll
    for (int ni = 0; ni < 4; ni++) {
      int col = cb0 + ni * 16 + rr;
      float bv = bias[col];
      #pragma unroll
      for (int mi = 0; mi < 8; mi++) {
        #pragma unroll
        for (int r = 0; r < 4; r++) {
          int row = rb0 + mi * 16 + g * 4 + r;
          float val = acc[mi][ni][r] + bv;
          if (MODE == 1) {
            int w = row >> 6, t = row & 63;
            int b = w >> 6, win = w & 63;
            int i2 = win >> 3, j2 = win & 7, s1 = t >> 3, s2 = t & 7;
            int pos = (b << 12) + (s1 * 8 + i2) * 64 + (s2 * 8 + j2);
            size_t idx = (size_t)pos * 512 + col;
            fo[idx] = resid[idx] + val;
          } else {
            size_t idx = (size_t)row * 512 + col;
            fo[idx] += val;
          }
        }
      }
    }
  }
}

// ---------------- attention: one wave per (window, head) ----------------
DEVI int zone1(int x) { return x < 56 ? 0 : (x < 60 ? 1 : 2); }

__global__ __launch_bounds__(256) void attn_k(const u16* __restrict__ qb,
                                              const u16* __restrict__ kb,
                                              const u16* __restrict__ vtb,
                                              const float* __restrict__ rpb,
                                              u16* __restrict__ outb) {
  __shared__ u16 P[4][64][72];
  int wid = threadIdx.x >> 6, lane = threadIdx.x & 63;
  int p = blockIdx.x * 4 + wid;
  int w = p >> 4, head = p & 15;
  const u16* qq = qb  + (size_t)p * 2048;
  const u16* kk = kb  + (size_t)p * 2048;
  const u16* vv = vtb + (size_t)p * 2048;
  int rr = lane & 15, g = lane >> 4;

  short8 qf[4], kf[4];
  #pragma unroll
  for (int i = 0; i < 4; i++) qf[i] = *(const short8*)(qq + (i*16 + rr)*32 + g*8);
  #pragma unroll
  for (int i = 0; i < 4; i++) kf[i] = *(const short8*)(kk + (i*16 + rr)*32 + g*8);

  f32x4 zero = {0.f, 0.f, 0.f, 0.f};
  f32x4 s[4][4];
  #pragma unroll
  for (int qi = 0; qi < 4; qi++)
    #pragma unroll
    for (int kj = 0; kj < 4; kj++)
      s[qi][kj] = __builtin_amdgcn_mfma_f32_16x16x32_bf16(qf[qi], kf[kj], zero, 0, 0, 0);

  int win = w & 63, i2 = win >> 3, j2 = win & 7;
  #pragma unroll
  for (int qi = 0; qi < 4; qi++) {
    #pragma unroll
    for (int r = 0; r < 4; r++) {
      int i = qi*16 + g*4 + r;
      int s1i = i >> 3, s2i = i & 7;
      int zi = zone1(s1i*8 + i2)*3 + zone1(s2i*8 + j2);
      #pragma unroll
      for (int kj = 0; kj < 4; kj++) {
        int j = kj*16 + rr;
        int s1j = j >> 3, s2j = j & 7;
        float bv = rpb[((s1i - s1j + 7)*15 + (s2i - s2j + 7))*16 + head];
        int zj = zone1(s1j*8 + i2)*3 + zone1(s2j*8 + j2);
        s[qi][kj][r] += bv + (zi != zj ? -1e10f : 0.f);
      }
    }
  }

  float inv[4][4];
  #pragma unroll
  for (int qi = 0; qi < 4; qi++) {
    #pragma unroll
    for (int r = 0; r < 4; r++) {
      float mx = fmaxf(fmaxf(s[qi][0][r], s[qi][1][r]), fmaxf(s[qi][2][r], s[qi][3][r]));
      mx = fmaxf(mx, __shfl_xor(mx, 1));
      mx = fmaxf(mx, __shfl_xor(mx, 2));
      mx = fmaxf(mx, __shfl_xor(mx, 4));
      mx = fmaxf(mx, __shfl_xor(mx, 8));
      float sum = 0.f;
      #pragma unroll
      for (int kj = 0; kj < 4; kj++) {
        float e = __expf(s[qi][kj][r] - mx);
        s[qi][kj][r] = e;
        sum += e;
      }
      sum += __shfl_xor(sum, 1);
      sum += __shfl_xor(sum, 2);
      sum += __shfl_xor(sum, 4);
      sum += __shfl_xor(sum, 8);
      inv[qi][r] = 1.f / sum;
    }
  }

  #pragma unroll
  for (int qi = 0; qi < 4; qi++)
    #pragma unroll
    for (int kj = 0; kj < 4; kj++)
      #pragma unroll
      for (int r = 0; r < 4; r++)
        P[wid][qi*16 + g*4 + r][kj*16 + rr] = f2bf(s[qi][kj][r]);

  f32x4 o[4][2] = {};
  #pragma unroll
  for (int jh = 0; jh < 2; jh++) {
    short8 vf[2];
    #pragma unroll
    for (int df = 0; df < 2; df++)
      vf[df] = *(const short8*)(vv + (size_t)(df*16 + rr)*64 + jh*32 + g*8);
    #pragma unroll
    for (int qi = 0; qi < 4; qi++) {
      short8 pf = *(const short8*)(&P[wid][qi*16 + rr][jh*32 + g*8]);
      #pragma unroll
      for (int df = 0; df < 2; df++)
        o[qi][df] = __builtin_amdgcn_mfma_f32_16x16x32_bf16(pf, vf[df], o[qi][df], 0, 0, 0);
    }
  }

  #pragma unroll
  for (int qi = 0; qi < 4; qi++)
    #pragma unroll
    for (int df = 0; df < 2; df++)
      #pragma unroll
      for (int r = 0; r < 4; r++) {
        int t = qi*16 + g*4 + r;
        int d = df*16 + rr;
        outb[(size_t)(w*64 + t)*512 + head*32 + d] = f2bf(o[qi][df][r] * inv[qi][r]);
      }
}

extern "C" void kernel_launch(void* const* d_in, const int* in_sizes, int n_in,
                              void* d_out, int out_size, void* d_ws, size_t ws_size,
                              hipStream_t stream) {
  const float* x     = (const float*)d_in[0];
  const float* ln1w  = (const float*)d_in[1];
  const float* ln1b  = (const float*)d_in[2];
  const float* qkvw  = (const float*)d_in[3];
  const float* qkvb  = (const float*)d_in[4];
  const float* rpb   = (const float*)d_in[5];
  const float* projw = (const float*)d_in[6];
  const float* projb = (const float*)d_in[7];
  const float* ln2w  = (const float*)d_in[8];
  const float* ln2b  = (const float*)d_in[9];
  const float* fc1w  = (const float*)d_in[10];
  const float* fc1b  = (const float*)d_in[11];
  const float* fc2w  = (const float*)d_in[12];
  const float* fc2b  = (const float*)d_in[13];
  float* out = (float*)d_out;

  char* ws = (char*)d_ws;
  u16* wqkv  = (u16*)(ws + 0);         // 786432 el (permuted cols)
  u16* wproj = (u16*)(ws + 1572864);   // 262144 el
  u16* wfc1  = (u16*)(ws + 2097152);   // 1048576 el
  u16* wfc2  = (u16*)(ws + 4194304);   // 1048576 el
  float* pb  = (float*)(ws + 6291456); // 1536 el (permuted qkv bias)
  size_t base = 8ull << 20;
  u16* xw = (u16*)(ws + base);                      // 64 MiB  (aliased later: attn, z)
  u16* qb = (u16*)(ws + base + (64ull  << 20));     // 64 MiB  (aliased later: part of h)
  u16* kb = (u16*)(ws + base + (128ull << 20));     // 64 MiB
  u16* vb = (u16*)(ws + base + (192ull << 20));     // 64 MiB
  u16* attnb = xw;
  u16* zb    = xw;
  u16* hb    = qb;                                  // 256 MiB -> ws end 328 MiB

  // weights -> bf16 (qkv permuted)
  cvt_qkvw<<<768, 256, 0, stream>>>((const float4*)qkvw, (us4*)wqkv);
  perm_qkvb<<<6, 256, 0, stream>>>(qkvb, pb);
  cvt_bf16<<<256,  256, 0, stream>>>((const float4*)projw, (us4*)wproj, 65536);
  cvt_bf16<<<1024, 256, 0, stream>>>((const float4*)fc1w,  (us4*)wfc1,  262144);
  cvt_bf16<<<1024, 256, 0, stream>>>((const float4*)fc2w,  (us4*)wfc2,  262144);

  // LN1 + roll + window partition
  ln_kernel<true><<<16384, 256, 0, stream>>>(x, ln1w, ln1b, xw);
  // QKV: grid (65536/256) x (1536/256) = 1536
  gemm_k<0><<<1536, 512, 0, stream>>>(xw, wqkv, pb, qb, kb, vb, nullptr, nullptr,
                                      65536, 1536, 512);
  // attention
  attn_k<<<4096, 256, 0, stream>>>(qb, kb, vb, rpb, attnb);
  // proj + win_reverse + residual -> d_out (= x2): 256 x 2 = 512
  gemm_k<1><<<512, 512, 0, stream>>>(attnb, wproj, projb, nullptr, nullptr, nullptr,
                                     out, x, 65536, 512, 512);
  // LN2
  ln_kernel<false><<<16384, 256, 0, stream>>>(out, ln2w, ln2b, zb);
  // fc1 + gelu: 256 x 8 = 2048
  gemm_k<2><<<2048, 512, 0, stream>>>(zb, wfc1, fc1b, hb, nullptr, nullptr, nullptr, nullptr,
                                      65536, 2048, 512);
  // fc2 + residual (in-place on d_out): 256 x 2 = 512
  gemm_k<3><<<512, 512, 0, stream>>>(hb, wfc2, fc2b, nullptr, nullptr, nullptr, out, nullptr,
                                     65536, 512, 2048);
}

// Round 7
// 887.119 us; speedup vs baseline: 5.0253x; 5.0253x over previous
//
#include <hip/hip_runtime.h>
#include <math.h>

typedef short short8 __attribute__((ext_vector_type(8)));
typedef float f32x4 __attribute__((ext_vector_type(4)));
typedef unsigned short u16;
typedef u16 us4 __attribute__((ext_vector_type(4)));

#define DEVI static __device__ __forceinline__

constexpr float SCALE_Q = 0.17677669529663687f;  // 32^-0.5

DEVI u16 f2bf(float f) {
  unsigned u = __builtin_bit_cast(unsigned, f);
  u += 0x7FFFu + ((u >> 16) & 1u);
  return (u16)(u >> 16);
}

// async global->LDS, 16B per lane; lds dest = wave-uniform base + lane*16
DEVI void gload16(const u16* g, u16* l) {
  __builtin_amdgcn_global_load_lds((const __attribute__((address_space(1))) void*)g,
                                   (__attribute__((address_space(3))) void*)l,
                                   16, 0, 0);
}

// ---------------- weight fp32 -> bf16 ----------------
__global__ void cvt_bf16(const float4* __restrict__ src, us4* __restrict__ dst, int n4) {
  int i = blockIdx.x * 256 + threadIdx.x;
  if (i < n4) {
    float4 v = src[i];
    us4 o = { f2bf(v.x), f2bf(v.y), f2bf(v.z), f2bf(v.w) };
    dst[i] = o;
  }
}

// qkv weights: permute rows so out col' = which*512 + head*32 + d  (src col = head*96 + d*3 + which)
__global__ void cvt_qkvw(const float4* __restrict__ src, us4* __restrict__ dst) {
  int i = blockIdx.x * 256 + threadIdx.x;   // 1536 rows x 128 float4
  int row = i >> 7, c4 = i & 127;
  int which = row >> 9, head = (row >> 5) & 15, d = row & 31;
  int srow = head * 96 + d * 3 + which;
  float4 v = src[srow * 128 + c4];
  us4 o = { f2bf(v.x), f2bf(v.y), f2bf(v.z), f2bf(v.w) };
  dst[i] = o;
}

__global__ void perm_qkvb(const float* __restrict__ src, float* __restrict__ dst) {
  int i = blockIdx.x * 256 + threadIdx.x;   // 1536
  int which = i >> 9, head = (i >> 5) & 15, d = i & 31;
  dst[i] = src[head * 96 + d * 3 + which];
}

// ---------------- LayerNorm (+ optional roll + dilated window partition) ----------------
template<bool PERM>
__global__ __launch_bounds__(256) void ln_kernel(const float* __restrict__ src,
                                                 const float* __restrict__ gw,
                                                 const float* __restrict__ gb,
                                                 u16* __restrict__ dst) {
  int wid = threadIdx.x >> 6, lane = threadIdx.x & 63;
  int m = blockIdx.x * 4 + wid;
  int srow;
  if (PERM) {
    int b = m >> 12;
    int win = (m >> 6) & 63, t = m & 63;
    int i2 = win >> 3, j2 = win & 7, s1 = t >> 3, s2 = t & 7;
    int h = (s1 * 8 + i2 + 4) & 63, w = (s2 * 8 + j2 + 4) & 63;
    srow = (b << 12) + h * 64 + w;
  } else {
    srow = m;
  }
  const float4* r4 = (const float4*)(src + (size_t)srow * 512);
  float4 v0 = r4[lane], v1 = r4[lane + 64];
  float s  = v0.x + v0.y + v0.z + v0.w + v1.x + v1.y + v1.z + v1.w;
  float ss = v0.x*v0.x + v0.y*v0.y + v0.z*v0.z + v0.w*v0.w
           + v1.x*v1.x + v1.y*v1.y + v1.z*v1.z + v1.w*v1.w;
  #pragma unroll
  for (int off = 1; off < 64; off <<= 1) {
    s  += __shfl_xor(s, off);
    ss += __shfl_xor(ss, off);
  }
  float mean = s * (1.f/512.f);
  float var  = ss * (1.f/512.f) - mean*mean;
  float rstd = rsqrtf(var + 1e-5f);
  const float4* w4 = (const float4*)gw;
  const float4* b4 = (const float4*)gb;
  float4 wa = w4[lane], ba = b4[lane], wb = w4[lane+64], bb = b4[lane+64];
  us4 o0 = { f2bf((v0.x-mean)*rstd*wa.x + ba.x),
             f2bf((v0.y-mean)*rstd*wa.y + ba.y),
             f2bf((v0.z-mean)*rstd*wa.z + ba.z),
             f2bf((v0.w-mean)*rstd*wa.w + ba.w) };
  us4 o1 = { f2bf((v1.x-mean)*rstd*wb.x + bb.x),
             f2bf((v1.y-mean)*rstd*wb.y + bb.y),
             f2bf((v1.z-mean)*rstd*wb.z + bb.z),
             f2bf((v1.w-mean)*rstd*wb.w + bb.w) };
  us4* d4 = (us4*)(dst + (size_t)m * 512);
  d4[lane] = o0; d4[lane + 64] = o1;
}

// ---------------- GEMM: C[M,N] = A[M,K](bf16) @ W[N,K]^T(bf16) + bias ----
// m201-style 8-phase: 256x256 tile, BK=64, 8 waves (2Mx4N), 2 dbuf x (A,B) x 2 K-halves
// = 128 KiB LDS. 4 phases/K-tile, each: {ds_read subtile | stage 1 half (2 gload16) |
// barrier | lgkm0 | setprio MFMA x16 | barrier}. Counted vmcnt(4) at end of phases 1,3
// (never 0 in steady state); vmcnt(0) only for the final tile.
// Swizzle: 16B-chunk ^= (row&3) on stage source AND ds_read (64B rows).
// MODE 0: qkv (permuted cols: tn 0-1 q(scaled), 2-3 k, 4-5 v(transposed))
// MODE 1: proj: fo[win_reverse(row), col] = resid[same] + val (fp32 direct)
// MODE 2: fc1: gelu(tanh-approx) -> o0 bf16 row-major
// MODE 3: fc2: fo[row*512+col] += val (fp32 direct)
template<int MODE>
__global__ __launch_bounds__(512, 1) void gemm_k(const u16* __restrict__ A,
                                                 const u16* __restrict__ Bw,
                                                 const float* __restrict__ bias,
                                                 u16* __restrict__ o0, u16* __restrict__ o1,
                                                 u16* __restrict__ o2,
                                                 float* __restrict__ fo,
                                                 const float* __restrict__ resid,
                                                 int M, int N, int K) {
  __shared__ u16 LDS[2][2][2][8192];   // [buf][opA/B][khalf][256 rows x 32 k]
  int nt = N >> 8;
  int nwg = gridDim.x, cpx = nwg >> 3, bid = blockIdx.x;
  int swz = (bid & 7) * cpx + (bid >> 3);
  int tm = swz / nt, tn = swz % nt;
  int tid = threadIdx.x, lane = tid & 63, wv = tid >> 6;
  int wm = wv >> 2, wn = wv & 3;       // 2 M-halves x 4 N-quarters
  int rr = lane & 15, g = lane >> 4;
  int NT = K >> 6;

  // staging source: thread covers rows (tid>>2) and +128 at 16B-chunk (tid&3),
  // source k-chunk pre-XORed by (row&3) so linear LDS dest + XOR'd ds_read match.
  int srow = tid >> 2;
  int sch = ((tid & 3) ^ (srow & 3)) << 3;
  const u16* a0 = A  + (size_t)(tm * 256 + srow) * K + sch;
  const u16* b0 = Bw + (size_t)(tn * 256 + srow) * K + sch;
  size_t rsk = (size_t)128 * K;

#define STG(op, kh, buf, ktt) { \
    u16* d = &LDS[buf][op][kh][0] + (wv << 9); \
    const u16* s = ((op) ? b0 : a0) + (ktt) * 64 + (kh) * 32; \
    gload16(s, d); gload16(s + rsk, d + 4096); }

  f32x4 acc[8][4] = {};

  // prologue: all 4 halves of tile 0 -> buf 0; wait k0 halves (k1 stay in flight)
  STG(0, 0, 0, 0); STG(1, 0, 0, 0); STG(0, 1, 0, 0); STG(1, 1, 0, 0);
  asm volatile("s_waitcnt vmcnt(4)" ::: "memory");
  __builtin_amdgcn_s_barrier();

  for (int kt = 0; kt < NT; ++kt) {
    int c = kt & 1;
    bool st = (kt + 1 < NT);
    short8 bf[4], af[4];
    // ---- phase 0: ks=0, mi 0-3 (+ stage A,k0 of kt+1) ----
    {
      const u16* Ak = &LDS[c][0][0][0];
      const u16* Bk = &LDS[c][1][0][0];
      #pragma unroll
      for (int ni = 0; ni < 4; ni++) { int r = wn*64 + ni*16 + rr;
        bf[ni] = *(const short8*)(Bk + r*32 + ((g ^ (r & 3)) << 3)); }
      #pragma unroll
      for (int mi = 0; mi < 4; mi++) { int r = wm*128 + mi*16 + rr;
        af[mi] = *(const short8*)(Ak + r*32 + ((g ^ (r & 3)) << 3)); }
      if (st) STG(0, 0, c ^ 1, kt + 1);
      __builtin_amdgcn_s_barrier();
      asm volatile("s_waitcnt lgkmcnt(0)" ::: "memory");
      __builtin_amdgcn_sched_barrier(0);
      __builtin_amdgcn_s_setprio(1);
      #pragma unroll
      for (int mi = 0; mi < 4; mi++)
        #pragma unroll
        for (int ni = 0; ni < 4; ni++)
          acc[mi][ni] = __builtin_amdgcn_mfma_f32_16x16x32_bf16(af[mi], bf[ni], acc[mi][ni], 0, 0, 0);
      __builtin_amdgcn_s_setprio(0);
      __builtin_amdgcn_s_barrier();
    }
    // ---- phase 1: ks=0, mi 4-7 (+ stage B,k0 of kt+1; end: wait kt's k1 halves) ----
    {
      const u16* Ak = &LDS[c][0][0][0];
      #pragma unroll
      for (int mi = 0; mi < 4; mi++) { int r = wm*128 + 64 + mi*16 + rr;
        af[mi] = *(const short8*)(Ak + r*32 + ((g ^ (r & 3)) << 3)); }
      if (st) STG(1, 0, c ^ 1, kt + 1);
      __builtin_amdgcn_s_barrier();
      asm volatile("s_waitcnt lgkmcnt(0)" ::: "memory");
      __builtin_amdgcn_sched_barrier(0);
      __builtin_amdgcn_s_setprio(1);
      #pragma unroll
      for (int mi = 0; mi < 4; mi++)
        #pragma unroll
        for (int ni = 0; ni < 4; ni++)
          acc[4 + mi][ni] = __builtin_amdgcn_mfma_f32_16x16x32_bf16(af[mi], bf[ni], acc[4 + mi][ni], 0, 0, 0);
      __builtin_amdgcn_s_setprio(0);
      if (st) { asm volatile("s_waitcnt vmcnt(4)" ::: "memory"); }
      else    { asm volatile("s_waitcnt vmcnt(0)" ::: "memory"); }
      __builtin_amdgcn_s_barrier();
    }
    // ---- phase 2: ks=1, mi 0-3 (+ stage A,k1 of kt+1) ----
    {
      const u16* Ak = &LDS[c][0][1][0];
      const u16* Bk = &LDS[c][1][1][0];
      #pragma unroll
      for (int ni = 0; ni < 4; ni++) { int r = wn*64 + ni*16 + rr;
        bf[ni] = *(const short8*)(Bk + r*32 + ((g ^ (r & 3)) << 3)); }
      #pragma unroll
      for (int mi = 0; mi < 4; mi++) { int r = wm*128 + mi*16 + rr;
        af[mi] = *(const short8*)(Ak + r*32 + ((g ^ (r & 3)) << 3)); }
      if (st) STG(0, 1, c ^ 1, kt + 1);
      __builtin_amdgcn_s_barrier();
      asm volatile("s_waitcnt lgkmcnt(0)" ::: "memory");
      __builtin_amdgcn_sched_barrier(0);
      __builtin_amdgcn_s_setprio(1);
      #pragma unroll
      for (int mi = 0; mi < 4; mi++)
        #pragma unroll
        for (int ni = 0; ni < 4; ni++)
          acc[mi][ni] = __builtin_amdgcn_mfma_f32_16x16x32_bf16(af[mi], bf[ni], acc[mi][ni], 0, 0, 0);
      __builtin_amdgcn_s_setprio(0);
      __builtin_amdgcn_s_barrier();
    }
    // ---- phase 3: ks=1, mi 4-7 (+ stage B,k1 of kt+1; end: wait kt+1's k0 halves) ----
    {
      const u16* Ak = &LDS[c][0][1][0];
      #pragma unroll
      for (int mi = 0; mi < 4; mi++) { int r = wm*128 + 64 + mi*16 + rr;
        af[mi] = *(const short8*)(Ak + r*32 + ((g ^ (r & 3)) << 3)); }
      if (st) STG(1, 1, c ^ 1, kt + 1);
      __builtin_amdgcn_s_barrier();
      asm volatile("s_waitcnt lgkmcnt(0)" ::: "memory");
      __builtin_amdgcn_sched_barrier(0);
      __builtin_amdgcn_s_setprio(1);
      #pragma unroll
      for (int mi = 0; mi < 4; mi++)
        #pragma unroll
        for (int ni = 0; ni < 4; ni++)
          acc[4 + mi][ni] = __builtin_amdgcn_mfma_f32_16x16x32_bf16(af[mi], bf[ni], acc[4 + mi][ni], 0, 0, 0);
      __builtin_amdgcn_s_setprio(0);
      if (st) { asm volatile("s_waitcnt vmcnt(4)" ::: "memory"); }
      __builtin_amdgcn_s_barrier();
    }
  }
#undef STG

  __syncthreads();   // full drain before LDS reuse
  u16* wreg = &LDS[0][0][0][0] + wv * 4096;   // wave-private 8 KiB bounce
  int rb0 = tm * 256 + wm * 128;
  int cb0 = tn * 256 + wn * 64;

  if (MODE == 0 || MODE == 2) {
    bool isV = (MODE == 0) && (tn >= 4);
    #pragma unroll
    for (int half = 0; half < 2; half++) {
      if (!isV) {
        #pragma unroll
        for (int mi2 = 0; mi2 < 4; mi2++)
          #pragma unroll
          for (int ni = 0; ni < 4; ni++) {
            float bv = bias[cb0 + ni * 16 + rr];
            #pragma unroll
            for (int r = 0; r < 4; r++) {
              float val = acc[half * 4 + mi2][ni][r] + bv;
              if (MODE == 2) {
                float u = val * (0.79788456f + 0.03567740814f * val * val);
                float e = __expf(2.f * u);
                val = val * (1.f - __builtin_amdgcn_rcpf(e + 1.f));
              }
              if (MODE == 0 && tn < 2) val *= SCALE_Q;
              int row = mi2 * 16 + g * 4 + r;
              int col = ni * 16 + rr;
              wreg[row * 64 + (((col >> 3) ^ (row & 7)) << 3) + (col & 7)] = f2bf(val);
            }
          }
        int row = lane;
        #pragma unroll
        for (int chk = 0; chk < 8; chk++) {
          short8 vd = *(const short8*)&wreg[row * 64 + ((chk ^ (row & 7)) << 3)];
          if (MODE == 2) {
            size_t grow = (size_t)rb0 + half * 64 + row;
            *(short8*)(o0 + grow * N + cb0 + chk * 8) = vd;
          } else {
            int grow = rb0 + half * 64 + row;
            int w = grow >> 6, tt = grow & 63;
            int head = ((cb0 & 511) >> 5) + (chk >> 2);
            u16* dst = (tn < 2) ? o0 : o1;
            *(short8*)(dst + ((size_t)(w * 16 + head) * 64 + tt) * 32 + (chk & 3) * 8) = vd;
          }
        }
      } else {
        // v: transposed deposit; half covers t-rows [half*64, half*64+64)
        #pragma unroll
        for (int mi2 = 0; mi2 < 4; mi2++)
          #pragma unroll
          for (int ni = 0; ni < 4; ni++) {
            float bv = bias[cb0 + ni * 16 + rr];
            #pragma unroll
            for (int r = 0; r < 4; r++) {
              float val = acc[half * 4 + mi2][ni][r] + bv;
              int row = mi2 * 16 + g * 4 + r;   // t within half (0..63)
              int col = ni * 16 + rr;           // d within wave cols (0..63)
              wreg[col * 64 + (((row >> 3) ^ (col & 7)) << 3) + (row & 7)] = f2bf(val);
            }
          }
        int cb0v = cb0 - 1024;
        int col = lane;
        int head = (cb0v + col) >> 5, d = (cb0v + col) & 31;
        int grow = rb0 + half * 64;
        int w = grow >> 6;
        #pragma unroll
        for (int chk = 0; chk < 8; chk++) {
          short8 vd = *(const short8*)&wreg[col * 64 + ((chk ^ (col & 7)) << 3)];
          *(short8*)(o2 + ((size_t)(w * 16 + head) * 32 + d) * 64 + (grow & 63) + chk * 8) = vd;
        }
      }
    }
  } else {
    #pragma unroll
    for (int ni = 0; ni < 4; ni++) {
      int col = cb0 + ni * 16 + rr;
      float bv = bias[col];
      #pragma unroll
      for (int mi = 0; mi < 8; mi++) {
        #pragma unroll
        for (int r = 0; r < 4; r++) {
          int row = rb0 + mi * 16 + g * 4 + r;
          float val = acc[mi][ni][r] + bv;
          if (MODE == 1) {
            int w = row >> 6, t = row & 63;
            int b = w >> 6, win = w & 63;
            int i2 = win >> 3, j2 = win & 7, s1 = t >> 3, s2 = t & 7;
            int pos = (b << 12) + (s1 * 8 + i2) * 64 + (s2 * 8 + j2);
            size_t idx = (size_t)pos * 512 + col;
            fo[idx] = resid[idx] + val;
          } else {
            size_t idx = (size_t)row * 512 + col;
            fo[idx] += val;
          }
        }
      }
    }
  }
}

// ---------------- attention: one wave per (window, head) ----------------
DEVI int zone1(int x) { return x < 56 ? 0 : (x < 60 ? 1 : 2); }

__global__ __launch_bounds__(256) void attn_k(const u16* __restrict__ qb,
                                              const u16* __restrict__ kb,
                                              const u16* __restrict__ vtb,
                                              const float* __restrict__ rpb,
                                              u16* __restrict__ outb) {
  __shared__ u16 P[4][64][72];
  int wid = threadIdx.x >> 6, lane = threadIdx.x & 63;
  int p = blockIdx.x * 4 + wid;
  int w = p >> 4, head = p & 15;
  const u16* qq = qb  + (size_t)p * 2048;
  const u16* kk = kb  + (size_t)p * 2048;
  const u16* vv = vtb + (size_t)p * 2048;
  int rr = lane & 15, g = lane >> 4;

  short8 qf[4], kf[4];
  #pragma unroll
  for (int i = 0; i < 4; i++) qf[i] = *(const short8*)(qq + (i*16 + rr)*32 + g*8);
  #pragma unroll
  for (int i = 0; i < 4; i++) kf[i] = *(const short8*)(kk + (i*16 + rr)*32 + g*8);

  f32x4 zero = {0.f, 0.f, 0.f, 0.f};
  f32x4 s[4][4];
  #pragma unroll
  for (int qi = 0; qi < 4; qi++)
    #pragma unroll
    for (int kj = 0; kj < 4; kj++)
      s[qi][kj] = __builtin_amdgcn_mfma_f32_16x16x32_bf16(qf[qi], kf[kj], zero, 0, 0, 0);

  int win = w & 63, i2 = win >> 3, j2 = win & 7;
  #pragma unroll
  for (int qi = 0; qi < 4; qi++) {
    #pragma unroll
    for (int r = 0; r < 4; r++) {
      int i = qi*16 + g*4 + r;
      int s1i = i >> 3, s2i = i & 7;
      int zi = zone1(s1i*8 + i2)*3 + zone1(s2i*8 + j2);
      #pragma unroll
      for (int kj = 0; kj < 4; kj++) {
        int j = kj*16 + rr;
        int s1j = j >> 3, s2j = j & 7;
        float bv = rpb[((s1i - s1j + 7)*15 + (s2i - s2j + 7))*16 + head];
        int zj = zone1(s1j*8 + i2)*3 + zone1(s2j*8 + j2);
        s[qi][kj][r] += bv + (zi != zj ? -1e10f : 0.f);
      }
    }
  }

  float inv[4][4];
  #pragma unroll
  for (int qi = 0; qi < 4; qi++) {
    #pragma unroll
    for (int r = 0; r < 4; r++) {
      float mx = fmaxf(fmaxf(s[qi][0][r], s[qi][1][r]), fmaxf(s[qi][2][r], s[qi][3][r]));
      mx = fmaxf(mx, __shfl_xor(mx, 1));
      mx = fmaxf(mx, __shfl_xor(mx, 2));
      mx = fmaxf(mx, __shfl_xor(mx, 4));
      mx = fmaxf(mx, __shfl_xor(mx, 8));
      float sum = 0.f;
      #pragma unroll
      for (int kj = 0; kj < 4; kj++) {
        float e = __expf(s[qi][kj][r] - mx);
        s[qi][kj][r] = e;
        sum += e;
      }
      sum += __shfl_xor(sum, 1);
      sum += __shfl_xor(sum, 2);
      sum += __shfl_xor(sum, 4);
      sum += __shfl_xor(sum, 8);
      inv[qi][r] = 1.f / sum;
    }
  }

  #pragma unroll
  for (int qi = 0; qi < 4; qi++)
    #pragma unroll
    for (int kj = 0; kj < 4; kj++)
      #pragma unroll
      for (int r = 0; r < 4; r++)
        P[wid][qi*16 + g*4 + r][kj*16 + rr] = f2bf(s[qi][kj][r]);

  f32x4 o[4][2] = {};
  #pragma unroll
  for (int jh = 0; jh < 2; jh++) {
    short8 vf[2];
    #pragma unroll
    for (int df = 0; df < 2; df++)
      vf[df] = *(const short8*)(vv + (size_t)(df*16 + rr)*64 + jh*32 + g*8);
    #pragma unroll
    for (int qi = 0; qi < 4; qi++) {
      short8 pf = *(const short8*)(&P[wid][qi*16 + rr][jh*32 + g*8]);
      #pragma unroll
      for (int df = 0; df < 2; df++)
        o[qi][df] = __builtin_amdgcn_mfma_f32_16x16x32_bf16(pf, vf[df], o[qi][df], 0, 0, 0);
    }
  }

  #pragma unroll
  for (int qi = 0; qi < 4; qi++)
    #pragma unroll
    for (int df = 0; df < 2; df++)
      #pragma unroll
      for (int r = 0; r < 4; r++) {
        int t = qi*16 + g*4 + r;
        int d = df*16 + rr;
        outb[(size_t)(w*64 + t)*512 + head*32 + d] = f2bf(o[qi][df][r] * inv[qi][r]);
      }
}

extern "C" void kernel_launch(void* const* d_in, const int* in_sizes, int n_in,
                              void* d_out, int out_size, void* d_ws, size_t ws_size,
                              hipStream_t stream) {
  const float* x     = (const float*)d_in[0];
  const float* ln1w  = (const float*)d_in[1];
  const float* ln1b  = (const float*)d_in[2];
  const float* qkvw  = (const float*)d_in[3];
  const float* qkvb  = (const float*)d_in[4];
  const float* rpb   = (const float*)d_in[5];
  const float* projw = (const float*)d_in[6];
  const float* projb = (const float*)d_in[7];
  const float* ln2w  = (const float*)d_in[8];
  const float* ln2b  = (const float*)d_in[9];
  const float* fc1w  = (const float*)d_in[10];
  const float* fc1b  = (const float*)d_in[11];
  const float* fc2w  = (const float*)d_in[12];
  const float* fc2b  = (const float*)d_in[13];
  float* out = (float*)d_out;

  char* ws = (char*)d_ws;
  u16* wqkv  = (u16*)(ws + 0);         // 786432 el (permuted cols)
  u16* wproj = (u16*)(ws + 1572864);   // 262144 el
  u16* wfc1  = (u16*)(ws + 2097152);   // 1048576 el
  u16* wfc2  = (u16*)(ws + 4194304);   // 1048576 el
  float* pb  = (float*)(ws + 6291456); // 1536 el (permuted qkv bias)
  size_t base = 8ull << 20;
  u16* xw = (u16*)(ws + base);                      // 64 MiB  (aliased later: attn, z)
  u16* qb = (u16*)(ws + base + (64ull  << 20));     // 64 MiB  (aliased later: part of h)
  u16* kb = (u16*)(ws + base + (128ull << 20));     // 64 MiB
  u16* vb = (u16*)(ws + base + (192ull << 20));     // 64 MiB
  u16* attnb = xw;
  u16* zb    = xw;
  u16* hb    = qb;                                  // 256 MiB -> ws end 328 MiB

  // weights -> bf16 (qkv permuted)
  cvt_qkvw<<<768, 256, 0, stream>>>((const float4*)qkvw, (us4*)wqkv);
  perm_qkvb<<<6, 256, 0, stream>>>(qkvb, pb);
  cvt_bf16<<<256,  256, 0, stream>>>((const float4*)projw, (us4*)wproj, 65536);
  cvt_bf16<<<1024, 256, 0, stream>>>((const float4*)fc1w,  (us4*)wfc1,  262144);
  cvt_bf16<<<1024, 256, 0, stream>>>((const float4*)fc2w,  (us4*)wfc2,  262144);

  // LN1 + roll + window partition
  ln_kernel<true><<<16384, 256, 0, stream>>>(x, ln1w, ln1b, xw);
  // QKV: grid (65536/256) x (1536/256) = 1536
  gemm_k<0><<<1536, 512, 0, stream>>>(xw, wqkv, pb, qb, kb, vb, nullptr, nullptr,
                                      65536, 1536, 512);
  // attention
  attn_k<<<4096, 256, 0, stream>>>(qb, kb, vb, rpb, attnb);
  // proj + win_reverse + residual -> d_out (= x2): 256 x 2 = 512
  gemm_k<1><<<512, 512, 0, stream>>>(attnb, wproj, projb, nullptr, nullptr, nullptr,
                                     out, x, 65536, 512, 512);
  // LN2
  ln_kernel<false><<<16384, 256, 0, stream>>>(out, ln2w, ln2b, zb);
  // fc1 + gelu: 256 x 8 = 2048
  gemm_k<2><<<2048, 512, 0, stream>>>(zb, wfc1, fc1b, hb, nullptr, nullptr, nullptr, nullptr,
                                      65536, 2048, 512);
  // fc2 + residual (in-place on d_out): 256 x 2 = 512
  gemm_k<3><<<512, 512, 0, stream>>>(hb, wfc2, fc2b, nullptr, nullptr, nullptr, out, nullptr,
                                     65536, 512, 2048);
}